// Round 3
// baseline (1850.287 us; speedup 1.0000x reference)
//
#include <hip/hip_runtime.h>
#include <hip/hip_bf16.h>

typedef _Float16 half8 __attribute__((ext_vector_type(8)));
typedef float floatx4 __attribute__((ext_vector_type(4)));

#define MFMA_F16(a, b, c) __builtin_amdgcn_mfma_f32_16x16x32_f16((a), (b), (c), 0, 0, 0)

// ---------------------------------------------------------------------------
// prep: f32 -> f16, optional transpose (dst[o*In+i] = src[i*Out+o]), scale
// ---------------------------------------------------------------------------
__global__ void prep_w_kernel(const float* __restrict__ src, _Float16* __restrict__ dst,
                              int In, int Out, float scale, int doT) {
  int idx = blockIdx.x * 256 + threadIdx.x;
  if (idx >= In * Out) return;
  float v;
  if (doT) { int o = idx / In, i = idx - o * In; v = src[i * Out + o]; }
  else     { v = src[idx]; }
  dst[idx] = (_Float16)(v * scale);
}

// ---------------------------------------------------------------------------
// phase 1: fused LN + dual GEMM.  grid (1536, 2), 256 threads.
//   y==0: kout[row][0..127]  = (LN(x) @ Wk) * S^-0.5   (scale baked into WT)
//   y==1: vT[bt][s][n]       = (LN(x) @ Wv)^T
// WT is [256 out][256 in] f16 (rows 0-127 = scaled Wk^T, 128-255 = Wv^T)
// ---------------------------------------------------------------------------
__global__ __launch_bounds__(256) void gemm_kv_kernel(
    const float* __restrict__ x, const float* __restrict__ lnw_g,
    const float* __restrict__ lnb_g, const _Float16* __restrict__ WT,
    _Float16* __restrict__ kout, _Float16* __restrict__ vTout) {
  __shared__ union {
    struct { _Float16 A[128][72]; _Float16 B[128][72]; } s;
    _Float16 C[128][136];
  } u;
  __shared__ float s_mean[128], s_rstd[128], s_red[256][2], s_lnw[256], s_lnb[256];

  const int tid = threadIdx.x;
  const int bx = blockIdx.x, y = blockIdx.y;
  const size_t r0 = (size_t)bx * 128;
  const int w = tid >> 6, lane = tid & 63, quad = lane >> 4, l15 = lane & 15;

  s_lnw[tid] = lnw_g[tid];
  s_lnb[tid] = lnb_g[tid];
  // row stats: 2 threads per row, 128 f32 each
  {
    int row = tid >> 1, half = tid & 1;
    const float* p = x + (r0 + row) * 256 + half * 128;
    float s = 0.f, sq = 0.f;
    for (int i = 0; i < 32; i++) {
      float4 d = ((const float4*)p)[i];
      s += d.x + d.y + d.z + d.w;
      sq += d.x * d.x + d.y * d.y + d.z * d.z + d.w * d.w;
    }
    s_red[tid][0] = s; s_red[tid][1] = sq;
  }
  __syncthreads();
  if (tid < 128) {
    float s  = s_red[2 * tid][0] + s_red[2 * tid + 1][0];
    float sq = s_red[2 * tid][1] + s_red[2 * tid + 1][1];
    float m = s * (1.f / 256.f);
    float v = sq * (1.f / 256.f) - m * m;
    s_mean[tid] = m; s_rstd[tid] = rsqrtf(v + 1e-5f);
  }

  floatx4 acc[2][8];
  for (int rt = 0; rt < 2; rt++)
    for (int ct = 0; ct < 8; ct++) acc[rt][ct] = (floatx4){0.f, 0.f, 0.f, 0.f};

  for (int c = 0; c < 4; c++) {        // K chunks of 64
    __syncthreads();
    for (int i = 0; i < 4; i++) {      // stage A (LN'd) and B
      int g = tid + 256 * i;
      int row = g >> 3, c8 = g & 7;
      int col0 = c * 64 + c8 * 8;
      const float* p = x + (r0 + row) * 256 + col0;
      float4 d0 = ((const float4*)p)[0];
      float4 d1 = ((const float4*)p)[1];
      float f[8] = {d0.x, d0.y, d0.z, d0.w, d1.x, d1.y, d1.z, d1.w};
      float m = s_mean[row], rs = s_rstd[row];
      half8 hv;
      #pragma unroll
      for (int j = 0; j < 8; j++)
        hv[j] = (_Float16)((f[j] - m) * rs * s_lnw[col0 + j] + s_lnb[col0 + j]);
      *(half8*)&u.s.A[row][c8 * 8] = hv;
      *(half8*)&u.s.B[row][c8 * 8] = *(const half8*)(WT + (size_t)(y * 128 + row) * 256 + col0);
    }
    __syncthreads();
    #pragma unroll
    for (int ks = 0; ks < 2; ks++) {
      half8 af[2];
      af[0] = *(const half8*)&u.s.A[(2 * w) * 16 + l15][ks * 32 + quad * 8];
      af[1] = *(const half8*)&u.s.A[(2 * w + 1) * 16 + l15][ks * 32 + quad * 8];
      #pragma unroll
      for (int ct = 0; ct < 8; ct++) {
        half8 bf = *(const half8*)&u.s.B[ct * 16 + l15][ks * 32 + quad * 8];
        acc[0][ct] = MFMA_F16(af[0], bf, acc[0][ct]);
        acc[1][ct] = MFMA_F16(af[1], bf, acc[1][ct]);
      }
    }
  }

  const size_t bt = (size_t)(bx >> 3);
  const int n0loc = (bx & 7) * 128;
  if (y == 0) {
    for (int rt = 0; rt < 2; rt++)
      for (int ct = 0; ct < 8; ct++)
        #pragma unroll
        for (int r = 0; r < 4; r++) {
          size_t row = r0 + (2 * w + rt) * 16 + quad * 4 + r;
          kout[row * 128 + ct * 16 + l15] = (_Float16)acc[rt][ct][r];
        }
  } else {
    __syncthreads();
    for (int rt = 0; rt < 2; rt++)
      for (int ct = 0; ct < 8; ct++)
        #pragma unroll
        for (int r = 0; r < 4; r++)
          u.C[(2 * w + rt) * 16 + quad * 4 + r][ct * 16 + l15] = (_Float16)acc[rt][ct][r];
    __syncthreads();
    int s = tid >> 1, hf = tid & 1;
    for (int j = 0; j < 8; j++) {
      int nb = hf * 64 + j * 8;
      half8 tmp;
      #pragma unroll
      for (int e = 0; e < 8; e++) tmp[e] = u.C[nb + e][s];
      *(half8*)(vTout + (bt * 128 + s) * 1024 + n0loc + nb) = tmp;
    }
  }
}

// ---------------------------------------------------------------------------
// phase 2: persistent per-batch slot-attention scan. grid 16, 1024 threads.
// ---------------------------------------------------------------------------
struct P2Args {
  const _Float16 *kbuf, *vT;
  const _Float16 *WqT, *Wih, *Whh, *W1T, *W2T;
  const _Float16 *pQT, *pKT, *pVT, *pOT, *pF1T, *pF2T;
  const float *noise, *mu, *lsig;
  const float *lnsw, *lnsb, *lnmw, *lnmb;
  const float *bih, *bhh, *mb1, *mb2;
  const float *pl1w, *pl1b, *pl2w, *pl2b, *fb1, *fb2, *plfw, *plfb;
  float *out_slots, *out_attn;
};

struct SH {
  float slots[8][128];
  _Float16 a16[16][136];
  _Float16 h16[16][136];
  union {
    struct { _Float16 qT[16][136]; _Float16 attnT[16][1032]; } sa;
    struct { float gi[8][384]; float gh[8][384]; } gru;
    struct { _Float16 m16[16][264]; } mlp;
    struct { float qh[8][128]; float kh[8][128]; float vh[8][128]; float sc[4][8][8]; } mha;
    struct { _Float16 f16[16][520]; } ffn;
  } u;
  float colsum[8];
  float vsum[128];
  float bih[384], bhh[384], mb1[256], mb2[128], fb1[512], fb2[128];
  float lnsw[128], lnsb[128], lnmw[128], lnmb[128];
  float pl1w[128], pl1b[128], pl2w[128], pl2b[128], plfw[128], plfb[128];
};

// LN rows 0..7 -> a16 rows 0..7; waves 8..15 zero-fill a16 rows 8..15
__device__ __forceinline__ void ln_to_a16(SH* sh, const float (*src)[128],
                                          const float* wv, const float* bv,
                                          int w, int lane) {
  if (w < 8) {
    float x0 = src[w][lane], x1 = src[w][lane + 64];
    float s = x0 + x1, sq = x0 * x0 + x1 * x1;
    #pragma unroll
    for (int m = 1; m < 64; m <<= 1) { s += __shfl_xor(s, m); sq += __shfl_xor(sq, m); }
    float mn = s * 0.0078125f;
    float vr = sq * 0.0078125f - mn * mn;
    float rs = rsqrtf(vr + 1e-5f);
    sh->a16[w][lane]      = (_Float16)((x0 - mn) * rs * wv[lane]      + bv[lane]);
    sh->a16[w][lane + 64] = (_Float16)((x1 - mn) * rs * wv[lane + 64] + bv[lane + 64]);
  } else {
    sh->a16[w][lane] = (_Float16)0.f;
    sh->a16[w][lane + 64] = (_Float16)0.f;
  }
}

__global__ __launch_bounds__(1024) void slot_attn_kernel(P2Args P) {
  __shared__ SH sh;
  const int tid = threadIdx.x;
  const int w = tid >> 6, lane = tid & 63, quad = lane >> 4, l15 = lane & 15;
  const int b = blockIdx.x;

  // one-time LDS clear: no stale NaN/Inf bit patterns anywhere
  for (int i = tid; i < (int)(sizeof(SH) / 4); i += 1024) ((float*)&sh)[i] = 0.f;
  __syncthreads();

  for (int i = tid; i < 384; i += 1024) { sh.bih[i] = P.bih[i]; sh.bhh[i] = P.bhh[i]; }
  for (int i = tid; i < 256; i += 1024) sh.mb1[i] = P.mb1[i];
  for (int i = tid; i < 512; i += 1024) sh.fb1[i] = P.fb1[i];
  if (tid < 128) {
    sh.mb2[tid]  = P.mb2[tid];  sh.fb2[tid]  = P.fb2[tid];
    sh.lnsw[tid] = P.lnsw[tid]; sh.lnsb[tid] = P.lnsb[tid];
    sh.lnmw[tid] = P.lnmw[tid]; sh.lnmb[tid] = P.lnmb[tid];
    sh.pl1w[tid] = P.pl1w[tid]; sh.pl1b[tid] = P.pl1b[tid];
    sh.pl2w[tid] = P.pl2w[tid]; sh.pl2b[tid] = P.pl2b[tid];
    sh.plfw[tid] = P.plfw[tid]; sh.plfb[tid] = P.plfb[tid];
  }
  {
    int kk = tid >> 7, s = tid & 127;
    sh.slots[kk][s] = P.mu[s] + expf(P.lsig[s]) * P.noise[(b * 8 + kk) * 128 + s];
  }
  __syncthreads();

  for (int t = 0; t < 12; t++) {
    const _Float16* kt = P.kbuf + ((size_t)(b * 12 + t)) * 1024 * 128;
    const _Float16* vt = P.vT   + ((size_t)(b * 12 + t)) * 128 * 1024;
    // vsum[s] = sum_n v[n][s]
    if (tid < 128) sh.vsum[tid] = 0.f;
    __syncthreads();
    {
      int s = tid >> 3, j8 = tid & 7;
      const _Float16* vr = vt + s * 1024 + j8 * 128;
      float a = 0.f;
      for (int i = 0; i < 16; i++) {
        half8 hv = *(const half8*)(vr + i * 8);
        #pragma unroll
        for (int e = 0; e < 8; e++) a += (float)hv[e];
      }
      atomicAdd(&sh.vsum[s], a);
    }

    for (int it = 0; it < 3; it++) {
      // ---- 1: y = LN(slots); h16 = f16(slots_prev); zero colsum
      if (w < 8) {
        float x0 = sh.slots[w][lane], x1 = sh.slots[w][lane + 64];
        sh.h16[w][lane] = (_Float16)x0; sh.h16[w][lane + 64] = (_Float16)x1;
        float s = x0 + x1, sq = x0 * x0 + x1 * x1;
        #pragma unroll
        for (int m = 1; m < 64; m <<= 1) { s += __shfl_xor(s, m); sq += __shfl_xor(sq, m); }
        float mn = s * 0.0078125f;
        float vr = sq * 0.0078125f - mn * mn;
        float rs = rsqrtf(vr + 1e-5f);
        sh.a16[w][lane]      = (_Float16)((x0 - mn) * rs * sh.lnsw[lane]      + sh.lnsb[lane]);
        sh.a16[w][lane + 64] = (_Float16)((x1 - mn) * rs * sh.lnsw[lane + 64] + sh.lnsb[lane + 64]);
      } else {
        sh.h16[w][lane] = (_Float16)0.f; sh.h16[w][lane + 64] = (_Float16)0.f;
        sh.a16[w][lane] = (_Float16)0.f; sh.a16[w][lane + 64] = (_Float16)0.f;
      }
      if (tid < 8) sh.colsum[tid] = 0.f;
      __syncthreads();
      // ---- 2: q = y @ Wq  (waves 0-7) -> qT[slot][i]
      if (w < 8) {
        floatx4 acc = (floatx4){0.f, 0.f, 0.f, 0.f};
        const _Float16* ar = &sh.a16[l15][quad * 8];
        const _Float16* br = P.WqT + (size_t)(w * 16 + l15) * 128 + quad * 8;
        #pragma unroll
        for (int ks = 0; ks < 4; ks++)
          acc = MFMA_F16(*(const half8*)(ar + ks * 32), *(const half8*)(br + ks * 32), acc);
        #pragma unroll
        for (int r = 0; r < 4; r++)
          sh.u.sa.qT[quad * 4 + r][w * 16 + l15] = (_Float16)acc[r];
      }
      __syncthreads();
      // ---- 3: logits = k_t @ q^T, softmax over slots, colsum
      {
        float cs = 0.f;
        for (int rr = 0; rr < 4; rr++) {
          int n0 = (w + 16 * rr) * 16;
          floatx4 acc = (floatx4){0.f, 0.f, 0.f, 0.f};
          const _Float16* ar = kt + (size_t)(n0 + l15) * 128 + quad * 8;
          const _Float16* br = &sh.u.sa.qT[l15][quad * 8];
          #pragma unroll
          for (int ks = 0; ks < 4; ks++)
            acc = MFMA_F16(*(const half8*)(ar + ks * 32), *(const half8*)(br + ks * 32), acc);
          #pragma unroll
          for (int r = 0; r < 4; r++) {
            float v = (l15 < 8) ? acc[r] : -3.0e38f;
            float mx = v;
            mx = fmaxf(mx, __shfl_xor(mx, 1, 16));
            mx = fmaxf(mx, __shfl_xor(mx, 2, 16));
            mx = fmaxf(mx, __shfl_xor(mx, 4, 16));
            mx = fmaxf(mx, __shfl_xor(mx, 8, 16));
            float pv = (l15 < 8) ? expf(v - mx) : 0.f;
            float ss = pv;
            ss += __shfl_xor(ss, 1, 16); ss += __shfl_xor(ss, 2, 16);
            ss += __shfl_xor(ss, 4, 16); ss += __shfl_xor(ss, 8, 16);
            float pn = pv / ss;
            cs += pn;
            int n = n0 + quad * 4 + r;
            sh.u.sa.attnT[l15][n] = (_Float16)pn;
            if (it == 2 && l15 < 8)
              P.out_attn[((size_t)(b * 12 + t) * 1024 + n) * 8 + l15] = pn;
          }
        }
        cs += __shfl_xor(cs, 16); cs += __shfl_xor(cs, 32);
        if (lane < 8) atomicAdd(&sh.colsum[lane], cs);
      }
      __syncthreads();
      // ---- 4: updates = P^T @ v (waves 0-7), fold +eps renorm, -> a16
      if (w < 8) {
        floatx4 acc = (floatx4){0.f, 0.f, 0.f, 0.f};
        const _Float16* ar = &sh.u.sa.attnT[l15][quad * 8];
        const _Float16* br = vt + (size_t)(w * 16 + l15) * 1024 + quad * 8;
        #pragma unroll 4
        for (int ks = 0; ks < 32; ks++)
          acc = MFMA_F16(*(const half8*)(ar + ks * 32), *(const half8*)(br + ks * 32), acc);
        int scol = w * 16 + l15;
        float vs = sh.vsum[scol] * 1e-8f;
        #pragma unroll
        for (int r = 0; r < 4; r++) {
          int slot = quad * 4 + r;
          if (slot < 8) {
            float inv = 1.f / (sh.colsum[slot] + 1024.f * 1e-8f);
            sh.a16[slot][scol] = (_Float16)((acc[r] + vs) * inv);
          } else {
            sh.a16[slot][scol] = (_Float16)0.f;
          }
        }
      }
      __syncthreads();
      // ---- 5: GRU gemms: gi = u@Wih^T + bih ; gh = h@Whh^T + bhh
      for (int j = w; j < 48; j += 16) {
        int isGi = (j < 24) ? 1 : 0;
        int ct = isGi ? j : j - 24;
        const _Float16* Ap = isGi ? &sh.a16[0][0] : &sh.h16[0][0];
        const _Float16* Bg = (isGi ? P.Wih : P.Whh) + (size_t)(ct * 16 + l15) * 128 + quad * 8;
        const _Float16* ar = Ap + l15 * 136 + quad * 8;
        floatx4 acc = (floatx4){0.f, 0.f, 0.f, 0.f};
        #pragma unroll
        for (int ks = 0; ks < 4; ks++)
          acc = MFMA_F16(*(const half8*)(ar + ks * 32), *(const half8*)(Bg + ks * 32), acc);
        int col = ct * 16 + l15;
        float bias = isGi ? sh.bih[col] : sh.bhh[col];
        float* dst = isGi ? &sh.u.gru.gi[0][0] : &sh.u.gru.gh[0][0];
        #pragma unroll
        for (int r = 0; r < 4; r++) {
          int slot = quad * 4 + r;
          if (slot < 8) dst[slot * 384 + col] = acc[r] + bias;
        }
      }
      __syncthreads();
      // ---- 6: gates
      {
        int kk = tid >> 7, s = tid & 127;
        float gr = sh.u.gru.gi[kk][s]       + sh.u.gru.gh[kk][s];
        float gz = sh.u.gru.gi[kk][128 + s] + sh.u.gru.gh[kk][128 + s];
        float rg = 1.f / (1.f + expf(-gr));
        float zg = 1.f / (1.f + expf(-gz));
        float ng = tanhf(sh.u.gru.gi[kk][256 + s] + rg * sh.u.gru.gh[kk][256 + s]);
        float h = sh.slots[kk][s];
        sh.slots[kk][s] = (1.f - zg) * ng + zg * h;
      }
      __syncthreads();
      // ---- 7: residual MLP (iters 0,1 only)
      if (it < 2) {
        ln_to_a16(&sh, sh.slots, sh.lnmw, sh.lnmb, w, lane);
        __syncthreads();
        {
          floatx4 acc = (floatx4){0.f, 0.f, 0.f, 0.f};
          const _Float16* ar = &sh.a16[l15][quad * 8];
          const _Float16* br = P.W1T + (size_t)(w * 16 + l15) * 128 + quad * 8;
          #pragma unroll
          for (int ks = 0; ks < 4; ks++)
            acc = MFMA_F16(*(const half8*)(ar + ks * 32), *(const half8*)(br + ks * 32), acc);
          int col = w * 16 + l15;
          #pragma unroll
          for (int r = 0; r < 4; r++) {
            int slot = quad * 4 + r;
            if (slot < 8) sh.u.mlp.m16[slot][col] = (_Float16)fmaxf(acc[r] + sh.mb1[col], 0.f);
            else          sh.u.mlp.m16[slot][col] = (_Float16)0.f;
          }
        }
        __syncthreads();
        if (w < 8) {
          floatx4 acc = (floatx4){0.f, 0.f, 0.f, 0.f};
          const _Float16* ar = &sh.u.mlp.m16[l15][quad * 8];
          const _Float16* br = P.W2T + (size_t)(w * 16 + l15) * 256 + quad * 8;
          #pragma unroll
          for (int ks = 0; ks < 8; ks++)
            acc = MFMA_F16(*(const half8*)(ar + ks * 32), *(const half8*)(br + ks * 32), acc);
          int col = w * 16 + l15;
          #pragma unroll
          for (int r = 0; r < 4; r++) {
            int slot = quad * 4 + r;
            if (slot < 8) sh.slots[slot][col] += acc[r] + sh.mb2[col];
          }
        }
        __syncthreads();
      }
    } // it

    // collect slots (pre-predictor)
    {
      int kk = tid >> 7, s = tid & 127;
      P.out_slots[((size_t)(b * 12 + t) * 8 + kk) * 128 + s] = sh.slots[kk][s];
    }
    // ---- predictor: s += MHA(LN1(s)); s += FFN(LN2(s)); s = LNf(s)
    ln_to_a16(&sh, sh.slots, sh.pl1w, sh.pl1b, w, lane);
    __syncthreads();
    for (int j = w; j < 24; j += 16) {   // q,k,v projections
      int g = j >> 3, ct = j & 7;
      const _Float16* Bg = (g == 0 ? P.pQT : (g == 1 ? P.pKT : P.pVT)) + (size_t)(ct * 16 + l15) * 128 + quad * 8;
      const _Float16* ar = &sh.a16[l15][quad * 8];
      floatx4 acc = (floatx4){0.f, 0.f, 0.f, 0.f};
      #pragma unroll
      for (int ks = 0; ks < 4; ks++)
        acc = MFMA_F16(*(const half8*)(ar + ks * 32), *(const half8*)(Bg + ks * 32), acc);
      float scale = (g == 0) ? 0.17677669529663687f : 1.f;
      float* dst = (g == 0 ? &sh.u.mha.qh[0][0] : (g == 1 ? &sh.u.mha.kh[0][0] : &sh.u.mha.vh[0][0]));
      int col = ct * 16 + l15;
      #pragma unroll
      for (int r = 0; r < 4; r++) {
        int slot = quad * 4 + r;
        if (slot < 8) dst[slot * 128 + col] = acc[r] * scale;
      }
    }
    __syncthreads();
    if (tid < 256) {   // scores
      int h = tid >> 6, a = (tid >> 3) & 7, b2 = tid & 7;
      const float* qr = &sh.u.mha.qh[a][h * 32];
      const float* kr = &sh.u.mha.kh[b2][h * 32];
      float s = 0.f;
      #pragma unroll
      for (int d = 0; d < 32; d++) s += qr[d] * kr[d];
      sh.u.mha.sc[h][a][b2] = s;
    }
    __syncthreads();
    if (tid < 32) {    // softmax over keys
      int h = tid >> 3, a = tid & 7;
      float* p = sh.u.mha.sc[h][a];
      float mx = p[0];
      #pragma unroll
      for (int j = 1; j < 8; j++) mx = fmaxf(mx, p[j]);
      float e[8]; float ssum = 0.f;
      #pragma unroll
      for (int j = 0; j < 8; j++) { e[j] = expf(p[j] - mx); ssum += e[j]; }
      float inv = 1.f / ssum;
      #pragma unroll
      for (int j = 0; j < 8; j++) p[j] = e[j] * inv;
    }
    __syncthreads();
    {                  // o = a @ v -> a16 rows 0..7
      int a = tid >> 7, col = tid & 127, h = col >> 5;
      float acc = 0.f;
      #pragma unroll
      for (int b2 = 0; b2 < 8; b2++) acc += sh.u.mha.sc[h][a][b2] * sh.u.mha.vh[b2][col];
      sh.a16[a][col] = (_Float16)acc;
    }
    __syncthreads();
    if (w < 8) {       // s += o @ Wo
      floatx4 acc = (floatx4){0.f, 0.f, 0.f, 0.f};
      const _Float16* ar = &sh.a16[l15][quad * 8];
      const _Float16* br = P.pOT + (size_t)(w * 16 + l15) * 128 + quad * 8;
      #pragma unroll
      for (int ks = 0; ks < 4; ks++)
        acc = MFMA_F16(*(const half8*)(ar + ks * 32), *(const half8*)(br + ks * 32), acc);
      int col = w * 16 + l15;
      #pragma unroll
      for (int r = 0; r < 4; r++) {
        int slot = quad * 4 + r;
        if (slot < 8) sh.slots[slot][col] += acc[r];
      }
    }
    __syncthreads();
    ln_to_a16(&sh, sh.slots, sh.pl2w, sh.pl2b, w, lane);
    __syncthreads();
    for (int ct = w; ct < 32; ct += 16) {   // FFN1 + relu (rows 8..15 -> 0)
      floatx4 acc = (floatx4){0.f, 0.f, 0.f, 0.f};
      const _Float16* ar = &sh.a16[l15][quad * 8];
      const _Float16* br = P.pF1T + (size_t)(ct * 16 + l15) * 128 + quad * 8;
      #pragma unroll
      for (int ks = 0; ks < 4; ks++)
        acc = MFMA_F16(*(const half8*)(ar + ks * 32), *(const half8*)(br + ks * 32), acc);
      int col = ct * 16 + l15;
      #pragma unroll
      for (int r = 0; r < 4; r++) {
        int slot = quad * 4 + r;
        if (slot < 8) sh.u.ffn.f16[slot][col] = (_Float16)fmaxf(acc[r] + sh.fb1[col], 0.f);
        else          sh.u.ffn.f16[slot][col] = (_Float16)0.f;
      }
    }
    __syncthreads();
    if (w < 8) {       // FFN2 + residual
      floatx4 acc = (floatx4){0.f, 0.f, 0.f, 0.f};
      const _Float16* ar = &sh.u.ffn.f16[l15][quad * 8];
      const _Float16* br = P.pF2T + (size_t)(w * 16 + l15) * 512 + quad * 8;
      #pragma unroll 4
      for (int ks = 0; ks < 16; ks++)
        acc = MFMA_F16(*(const half8*)(ar + ks * 32), *(const half8*)(br + ks * 32), acc);
      int col = w * 16 + l15;
      #pragma unroll
      for (int r = 0; r < 4; r++) {
        int slot = quad * 4 + r;
        if (slot < 8) sh.slots[slot][col] += acc[r] + sh.fb2[col];
      }
    }
    __syncthreads();
    if (w < 8) {       // final LN in place -> carry
      float x0 = sh.slots[w][lane], x1 = sh.slots[w][lane + 64];
      float s = x0 + x1, sq = x0 * x0 + x1 * x1;
      #pragma unroll
      for (int m = 1; m < 64; m <<= 1) { s += __shfl_xor(s, m); sq += __shfl_xor(sq, m); }
      float mn = s * 0.0078125f;
      float vr = sq * 0.0078125f - mn * mn;
      float rs = rsqrtf(vr + 1e-5f);
      sh.slots[w][lane]      = (x0 - mn) * rs * sh.plfw[lane]      + sh.plfb[lane];
      sh.slots[w][lane + 64] = (x1 - mn) * rs * sh.plfw[lane + 64] + sh.plfb[lane + 64];
    }
    __syncthreads();
  } // t
}

// ---------------------------------------------------------------------------
extern "C" void kernel_launch(void* const* d_in, const int* in_sizes, int n_in,
                              void* d_out, int out_size, void* d_ws, size_t ws_size,
                              hipStream_t stream) {
  const float* inp   = (const float*)d_in[0];
  const float* noise = (const float*)d_in[1];
  const float* mu    = (const float*)d_in[2];
  const float* lsig  = (const float*)d_in[3];
  const float* lniw  = (const float*)d_in[4];
  const float* lnib  = (const float*)d_in[5];
  const float* lnsw  = (const float*)d_in[6];
  const float* lnsb  = (const float*)d_in[7];
  const float* lnmw  = (const float*)d_in[8];
  const float* lnmb  = (const float*)d_in[9];
  const float* Wq    = (const float*)d_in[10];
  const float* Wk    = (const float*)d_in[11];
  const float* Wv    = (const float*)d_in[12];
  const float* gWih  = (const float*)d_in[13];
  const float* gWhh  = (const float*)d_in[14];
  const float* gbih  = (const float*)d_in[15];
  const float* gbhh  = (const float*)d_in[16];
  const float* mW1   = (const float*)d_in[17];
  const float* mb1   = (const float*)d_in[18];
  const float* mW2   = (const float*)d_in[19];
  const float* mb2   = (const float*)d_in[20];
  const float* pl1w  = (const float*)d_in[21];
  const float* pl1b  = (const float*)d_in[22];
  const float* pWq   = (const float*)d_in[23];
  const float* pWk   = (const float*)d_in[24];
  const float* pWv   = (const float*)d_in[25];
  const float* pWo   = (const float*)d_in[26];
  const float* pl2w  = (const float*)d_in[27];
  const float* pl2b  = (const float*)d_in[28];
  const float* pf1   = (const float*)d_in[29];
  const float* pfb1  = (const float*)d_in[30];
  const float* pf2   = (const float*)d_in[31];
  const float* pfb2  = (const float*)d_in[32];
  const float* plfw  = (const float*)d_in[33];
  const float* plfb  = (const float*)d_in[34];

  // workspace layout (f16 elements); total ~101.5 MB
  _Float16* p   = (_Float16*)d_ws;
  _Float16* kbuf = p;  p += 25165824;
  _Float16* vT   = p;  p += 25165824;
  _Float16* WT   = p;  p += 65536;
  _Float16* WqT  = p;  p += 16384;
  _Float16* Wih  = p;  p += 49152;
  _Float16* Whh  = p;  p += 49152;
  _Float16* W1T  = p;  p += 32768;
  _Float16* W2T  = p;  p += 32768;
  _Float16* pQT  = p;  p += 16384;
  _Float16* pKT  = p;  p += 16384;
  _Float16* pVT  = p;  p += 16384;
  _Float16* pOT  = p;  p += 16384;
  _Float16* pF1T = p;  p += 65536;
  _Float16* pF2T = p;  p += 65536;

  const float kscale = 0.08838834764831845f;  // S^-0.5, S=128
  prep_w_kernel<<<128, 256, 0, stream>>>(Wk,   WT,         256, 128, kscale, 1);
  prep_w_kernel<<<128, 256, 0, stream>>>(Wv,   WT + 32768, 256, 128, 1.f,    1);
  prep_w_kernel<<<64,  256, 0, stream>>>(Wq,   WqT,        128, 128, 1.f,    1);
  prep_w_kernel<<<192, 256, 0, stream>>>(gWih, Wih,        49152, 1, 1.f,    0);
  prep_w_kernel<<<192, 256, 0, stream>>>(gWhh, Whh,        49152, 1, 1.f,    0);
  prep_w_kernel<<<128, 256, 0, stream>>>(mW1,  W1T,        128, 256, 1.f,    1);
  prep_w_kernel<<<128, 256, 0, stream>>>(mW2,  W2T,        256, 128, 1.f,    1);
  prep_w_kernel<<<64,  256, 0, stream>>>(pWq,  pQT,        128, 128, 1.f,    1);
  prep_w_kernel<<<64,  256, 0, stream>>>(pWk,  pKT,        128, 128, 1.f,    1);
  prep_w_kernel<<<64,  256, 0, stream>>>(pWv,  pVT,        128, 128, 1.f,    1);
  prep_w_kernel<<<64,  256, 0, stream>>>(pWo,  pOT,        128, 128, 1.f,    1);
  prep_w_kernel<<<256, 256, 0, stream>>>(pf1,  pF1T,       128, 512, 1.f,    1);
  prep_w_kernel<<<256, 256, 0, stream>>>(pf2,  pF2T,       512, 128, 1.f,    1);

  dim3 g1(1536, 2, 1);
  gemm_kv_kernel<<<g1, 256, 0, stream>>>(inp, lniw, lnib, WT, kbuf, vT);

  P2Args a;
  a.kbuf = kbuf; a.vT = vT;
  a.WqT = WqT; a.Wih = Wih; a.Whh = Whh; a.W1T = W1T; a.W2T = W2T;
  a.pQT = pQT; a.pKT = pKT; a.pVT = pVT; a.pOT = pOT; a.pF1T = pF1T; a.pF2T = pF2T;
  a.noise = noise; a.mu = mu; a.lsig = lsig;
  a.lnsw = lnsw; a.lnsb = lnsb; a.lnmw = lnmw; a.lnmb = lnmb;
  a.bih = gbih; a.bhh = gbhh; a.mb1 = mb1; a.mb2 = mb2;
  a.pl1w = pl1w; a.pl1b = pl1b; a.pl2w = pl2w; a.pl2b = pl2b;
  a.fb1 = pfb1; a.fb2 = pfb2; a.plfw = plfw; a.plfb = plfb;
  a.out_slots = (float*)d_out;
  a.out_attn  = (float*)d_out + 196608;

  slot_attn_kernel<<<16, 1024, 0, stream>>>(a);
}

// Round 4
// 1375.295 us; speedup vs baseline: 1.3454x; 1.3454x over previous
//
#include <hip/hip_runtime.h>
#include <hip/hip_bf16.h>

typedef _Float16 half8 __attribute__((ext_vector_type(8)));
typedef float floatx4 __attribute__((ext_vector_type(4)));

#define MFMA_F16(a, b, c) __builtin_amdgcn_mfma_f32_16x16x32_f16((a), (b), (c), 0, 0, 0)

// ---------------------------------------------------------------------------
// prep: f32 -> f16, optional transpose (dst[o*In+i] = src[i*Out+o]), scale
// ---------------------------------------------------------------------------
__global__ void prep_w_kernel(const float* __restrict__ src, _Float16* __restrict__ dst,
                              int In, int Out, float scale, int doT) {
  int idx = blockIdx.x * 256 + threadIdx.x;
  if (idx >= In * Out) return;
  float v;
  if (doT) { int o = idx / In, i = idx - o * In; v = src[i * Out + o]; }
  else     { v = src[idx]; }
  dst[idx] = (_Float16)(v * scale);
}

__global__ void init_ctr_kernel(int* __restrict__ ctr) {
  if (threadIdx.x < 16) ctr[threadIdx.x] = 0;
}

// ---------------------------------------------------------------------------
// phase 1: fused LN + dual GEMM.  grid (1536, 2), 256 threads. (unchanged)
// ---------------------------------------------------------------------------
__global__ __launch_bounds__(256) void gemm_kv_kernel(
    const float* __restrict__ x, const float* __restrict__ lnw_g,
    const float* __restrict__ lnb_g, const _Float16* __restrict__ WT,
    _Float16* __restrict__ kout, _Float16* __restrict__ vTout) {
  __shared__ union {
    struct { _Float16 A[128][72]; _Float16 B[128][72]; } s;
    _Float16 C[128][136];
  } u;
  __shared__ float s_mean[128], s_rstd[128], s_red[256][2], s_lnw[256], s_lnb[256];

  const int tid = threadIdx.x;
  const int bx = blockIdx.x, y = blockIdx.y;
  const size_t r0 = (size_t)bx * 128;
  const int w = tid >> 6, lane = tid & 63, quad = lane >> 4, l15 = lane & 15;

  s_lnw[tid] = lnw_g[tid];
  s_lnb[tid] = lnb_g[tid];
  {
    int row = tid >> 1, half = tid & 1;
    const float* p = x + (r0 + row) * 256 + half * 128;
    float s = 0.f, sq = 0.f;
    for (int i = 0; i < 32; i++) {
      float4 d = ((const float4*)p)[i];
      s += d.x + d.y + d.z + d.w;
      sq += d.x * d.x + d.y * d.y + d.z * d.z + d.w * d.w;
    }
    s_red[tid][0] = s; s_red[tid][1] = sq;
  }
  __syncthreads();
  if (tid < 128) {
    float s  = s_red[2 * tid][0] + s_red[2 * tid + 1][0];
    float sq = s_red[2 * tid][1] + s_red[2 * tid + 1][1];
    float m = s * (1.f / 256.f);
    float v = sq * (1.f / 256.f) - m * m;
    s_mean[tid] = m; s_rstd[tid] = rsqrtf(v + 1e-5f);
  }

  floatx4 acc[2][8];
  for (int rt = 0; rt < 2; rt++)
    for (int ct = 0; ct < 8; ct++) acc[rt][ct] = (floatx4){0.f, 0.f, 0.f, 0.f};

  for (int c = 0; c < 4; c++) {
    __syncthreads();
    for (int i = 0; i < 4; i++) {
      int g = tid + 256 * i;
      int row = g >> 3, c8 = g & 7;
      int col0 = c * 64 + c8 * 8;
      const float* p = x + (r0 + row) * 256 + col0;
      float4 d0 = ((const float4*)p)[0];
      float4 d1 = ((const float4*)p)[1];
      float f[8] = {d0.x, d0.y, d0.z, d0.w, d1.x, d1.y, d1.z, d1.w};
      float m = s_mean[row], rs = s_rstd[row];
      half8 hv;
      #pragma unroll
      for (int j = 0; j < 8; j++)
        hv[j] = (_Float16)((f[j] - m) * rs * s_lnw[col0 + j] + s_lnb[col0 + j]);
      *(half8*)&u.s.A[row][c8 * 8] = hv;
      *(half8*)&u.s.B[row][c8 * 8] = *(const half8*)(WT + (size_t)(y * 128 + row) * 256 + col0);
    }
    __syncthreads();
    #pragma unroll
    for (int ks = 0; ks < 2; ks++) {
      half8 af[2];
      af[0] = *(const half8*)&u.s.A[(2 * w) * 16 + l15][ks * 32 + quad * 8];
      af[1] = *(const half8*)&u.s.A[(2 * w + 1) * 16 + l15][ks * 32 + quad * 8];
      #pragma unroll
      for (int ct = 0; ct < 8; ct++) {
        half8 bf = *(const half8*)&u.s.B[ct * 16 + l15][ks * 32 + quad * 8];
        acc[0][ct] = MFMA_F16(af[0], bf, acc[0][ct]);
        acc[1][ct] = MFMA_F16(af[1], bf, acc[1][ct]);
      }
    }
  }

  const size_t bt = (size_t)(bx >> 3);
  const int n0loc = (bx & 7) * 128;
  if (y == 0) {
    for (int rt = 0; rt < 2; rt++)
      for (int ct = 0; ct < 8; ct++)
        #pragma unroll
        for (int r = 0; r < 4; r++) {
          size_t row = r0 + (2 * w + rt) * 16 + quad * 4 + r;
          kout[row * 128 + ct * 16 + l15] = (_Float16)acc[rt][ct][r];
        }
  } else {
    __syncthreads();
    for (int rt = 0; rt < 2; rt++)
      for (int ct = 0; ct < 8; ct++)
        #pragma unroll
        for (int r = 0; r < 4; r++)
          u.C[(2 * w + rt) * 16 + quad * 4 + r][ct * 16 + l15] = (_Float16)acc[rt][ct][r];
    __syncthreads();
    int s = tid >> 1, hf = tid & 1;
    for (int j = 0; j < 8; j++) {
      int nb = hf * 64 + j * 8;
      half8 tmp;
      #pragma unroll
      for (int e = 0; e < 8; e++) tmp[e] = u.C[nb + e][s];
      *(half8*)(vTout + (bt * 128 + s) * 1024 + n0loc + nb) = tmp;
    }
  }
}

// ---------------------------------------------------------------------------
// phase 2: slot-attention scan. grid 128 (= 16 batches x 8 n-groups), 1024 thr.
// Each block owns n-slice [g*128, g*128+128); k/v slice LDS-resident per t.
// Cross-n reductions (colsum, P^T v, vsum) via global partials + 8-block
// device-scope barrier per iteration (double-buffered by iteration parity).
// Slot-state GEMMs computed redundantly (bit-identically) in all 8 blocks.
// ---------------------------------------------------------------------------
struct P2Args {
  const _Float16 *kbuf, *vT;
  const _Float16 *WqT, *Wih, *Whh, *W1T, *W2T;
  const _Float16 *pQT, *pKT, *pVT, *pOT, *pF1T, *pF2T;
  const float *noise, *mu, *lsig;
  const float *lnsw, *lnsb, *lnmw, *lnmb;
  const float *bih, *bhh, *mb1, *mb2;
  const float *pl1w, *pl1b, *pl2w, *pl2b, *fb1, *fb2, *plfw, *plfb;
  float *out_slots, *out_attn;
  float *upd_p;   // [2][16][8][8*128]
  float *col_p;   // [2][16][8][8]
  float *vs_p;    // [16][8][128]
  int   *ctr;     // [16]
};

struct SH {
  _Float16 k_lds[128][136];   // k slice [n_local][s]
  _Float16 v_lds[128][136];   // v slice [s][n_local]
  float slots[8][128];
  _Float16 a16[16][136];
  _Float16 h16[16][136];
  union {
    struct { _Float16 qT[16][136]; _Float16 attnT[16][136]; } sa;
    struct { float gi[8][384]; float gh[8][384]; } gru;
    struct { _Float16 m16[16][264]; } mlp;
    struct { float qh[8][128]; float kh[8][128]; float vh[8][128]; float sc[4][8][8]; } mha;
    struct { _Float16 f16[16][520]; } ffn;
  } u;
  float colsum[8];
  float vsum[128];
  float bih[384], bhh[384], mb1[256], mb2[128], fb1[512], fb2[128];
  float lnsw[128], lnsb[128], lnmw[128], lnmb[128];
  float pl1w[128], pl1b[128], pl2w[128], pl2b[128], plfw[128], plfb[128];
};

__device__ __forceinline__ void group_barrier(int* ctr, int target) {
  __syncthreads();   // drains vmcnt: all agent-scope stores complete
  if (threadIdx.x == 0) {
    __hip_atomic_fetch_add(ctr, 1, __ATOMIC_ACQ_REL, __HIP_MEMORY_SCOPE_AGENT);
    while (__hip_atomic_load(ctr, __ATOMIC_ACQUIRE, __HIP_MEMORY_SCOPE_AGENT) < target)
      __builtin_amdgcn_s_sleep(1);
  }
  __syncthreads();
}

__device__ __forceinline__ void ln_to_a16(SH* sh, const float (*src)[128],
                                          const float* wv, const float* bv,
                                          int w, int lane) {
  if (w < 8) {
    float x0 = src[w][lane], x1 = src[w][lane + 64];
    float s = x0 + x1, sq = x0 * x0 + x1 * x1;
    #pragma unroll
    for (int m = 1; m < 64; m <<= 1) { s += __shfl_xor(s, m); sq += __shfl_xor(sq, m); }
    float mn = s * 0.0078125f;
    float vr = sq * 0.0078125f - mn * mn;
    float rs = rsqrtf(vr + 1e-5f);
    sh->a16[w][lane]      = (_Float16)((x0 - mn) * rs * wv[lane]      + bv[lane]);
    sh->a16[w][lane + 64] = (_Float16)((x1 - mn) * rs * wv[lane + 64] + bv[lane + 64]);
  } else {
    sh->a16[w][lane] = (_Float16)0.f;
    sh->a16[w][lane + 64] = (_Float16)0.f;
  }
}

__global__ __launch_bounds__(1024) void slot_attn_kernel(P2Args P) {
  __shared__ SH sh;
  const int tid = threadIdx.x;
  const int w = tid >> 6, lane = tid & 63, quad = lane >> 4, l15 = lane & 15;
  const int b = blockIdx.x & 15;       // batch
  const int g = blockIdx.x >> 4;       // n-group (0..7) -> same XCD for fixed b
  const int n0 = g * 128;
  int* ctrb = P.ctr + b;
  int bar_phase = 0;

  for (int i = tid; i < 384; i += 1024) { sh.bih[i] = P.bih[i]; sh.bhh[i] = P.bhh[i]; }
  for (int i = tid; i < 256; i += 1024) sh.mb1[i] = P.mb1[i];
  for (int i = tid; i < 512; i += 1024) sh.fb1[i] = P.fb1[i];
  if (tid < 128) {
    sh.mb2[tid]  = P.mb2[tid];  sh.fb2[tid]  = P.fb2[tid];
    sh.lnsw[tid] = P.lnsw[tid]; sh.lnsb[tid] = P.lnsb[tid];
    sh.lnmw[tid] = P.lnmw[tid]; sh.lnmb[tid] = P.lnmb[tid];
    sh.pl1w[tid] = P.pl1w[tid]; sh.pl1b[tid] = P.pl1b[tid];
    sh.pl2w[tid] = P.pl2w[tid]; sh.pl2b[tid] = P.pl2b[tid];
    sh.plfw[tid] = P.plfw[tid]; sh.plfb[tid] = P.plfb[tid];
  }
  {
    int kk = tid >> 7, s = tid & 127;
    sh.slots[kk][s] = P.mu[s] + expf(P.lsig[s]) * P.noise[(b * 8 + kk) * 128 + s];
  }
  __syncthreads();

  for (int t = 0; t < 12; t++) {
    const _Float16* kt = P.kbuf + ((size_t)(b * 12 + t)) * 1024 * 128 + (size_t)n0 * 128;
    const _Float16* vt = P.vT   + ((size_t)(b * 12 + t)) * 128 * 1024 + n0;
    // ---- stage k/v slice into LDS (32 KB each)
    {
      int r = tid >> 4, c8 = (tid & 15) * 8;
      #pragma unroll
      for (int p = 0; p < 2; p++) {
        int row = p * 64 + r;
        *(half8*)&sh.k_lds[row][c8] = *(const half8*)(kt + (size_t)row * 128 + c8);
        *(half8*)&sh.v_lds[row][c8] = *(const half8*)(vt + (size_t)row * 1024 + c8);
      }
    }
    if (tid < 128) sh.vsum[tid] = 0.f;
    __syncthreads();
    // ---- vsum partial over local n from v_lds
    {
      int s = tid >> 3, j = tid & 7;
      float a = 0.f;
      #pragma unroll
      for (int e = 0; e < 16; e++) a += (float)sh.v_lds[s][j * 16 + e];
      atomicAdd(&sh.vsum[s], a);
    }
    __syncthreads();
    if (tid < 128)
      __hip_atomic_store(&P.vs_p[(b * 8 + g) * 128 + tid], sh.vsum[tid],
                         __ATOMIC_RELAXED, __HIP_MEMORY_SCOPE_AGENT);

    for (int it = 0; it < 3; it++) {
      const int par = (t * 3 + it) & 1;
      float* updg = P.upd_p + ((size_t)(par * 16 + b) * 8 + g) * 1024;
      float* colg = P.col_p + ((size_t)(par * 16 + b) * 8 + g) * 8;
      // ---- 1: y = LN(slots) -> a16 rows 0..7; h16 = f16(slots)
      if (w < 8) {
        float x0 = sh.slots[w][lane], x1 = sh.slots[w][lane + 64];
        sh.h16[w][lane] = (_Float16)x0; sh.h16[w][lane + 64] = (_Float16)x1;
        float s = x0 + x1, sq = x0 * x0 + x1 * x1;
        #pragma unroll
        for (int m = 1; m < 64; m <<= 1) { s += __shfl_xor(s, m); sq += __shfl_xor(sq, m); }
        float mn = s * 0.0078125f;
        float vr = sq * 0.0078125f - mn * mn;
        float rs = rsqrtf(vr + 1e-5f);
        sh.a16[w][lane]      = (_Float16)((x0 - mn) * rs * sh.lnsw[lane]      + sh.lnsb[lane]);
        sh.a16[w][lane + 64] = (_Float16)((x1 - mn) * rs * sh.lnsw[lane + 64] + sh.lnsb[lane + 64]);
      } else {
        sh.h16[w][lane] = (_Float16)0.f; sh.h16[w][lane + 64] = (_Float16)0.f;
        sh.a16[w][lane] = (_Float16)0.f; sh.a16[w][lane + 64] = (_Float16)0.f;
      }
      if (tid < 8) sh.colsum[tid] = 0.f;
      __syncthreads();
      // ---- 2: q = y @ Wq (waves 0-7) -> qT[s_col][slot-ish]
      if (w < 8) {
        floatx4 acc = (floatx4){0.f, 0.f, 0.f, 0.f};
        const _Float16* ar = &sh.a16[l15][quad * 8];
        const _Float16* br = P.WqT + (size_t)(w * 16 + l15) * 128 + quad * 8;
        #pragma unroll
        for (int ks = 0; ks < 4; ks++)
          acc = MFMA_F16(*(const half8*)(ar + ks * 32), *(const half8*)(br + ks * 32), acc);
        #pragma unroll
        for (int r = 0; r < 4; r++)
          sh.u.sa.qT[quad * 4 + r][w * 16 + l15] = (_Float16)acc[r];
      }
      __syncthreads();
      // ---- 3: logits (local 128 rows) from k_lds, softmax over slots, colsum
      if (w < 8) {
        int nloc0 = w * 16;
        floatx4 acc = (floatx4){0.f, 0.f, 0.f, 0.f};
        const _Float16* ar = &sh.k_lds[nloc0 + l15][quad * 8];
        const _Float16* br = &sh.u.sa.qT[l15][quad * 8];
        #pragma unroll
        for (int ks = 0; ks < 4; ks++)
          acc = MFMA_F16(*(const half8*)(ar + ks * 32), *(const half8*)(br + ks * 32), acc);
        float cs = 0.f;
        #pragma unroll
        for (int r = 0; r < 4; r++) {
          float v = (l15 < 8) ? acc[r] : -3.0e38f;
          float mx = v;
          mx = fmaxf(mx, __shfl_xor(mx, 1, 16));
          mx = fmaxf(mx, __shfl_xor(mx, 2, 16));
          mx = fmaxf(mx, __shfl_xor(mx, 4, 16));
          mx = fmaxf(mx, __shfl_xor(mx, 8, 16));
          float pv = (l15 < 8) ? expf(v - mx) : 0.f;
          float ss = pv;
          ss += __shfl_xor(ss, 1, 16); ss += __shfl_xor(ss, 2, 16);
          ss += __shfl_xor(ss, 4, 16); ss += __shfl_xor(ss, 8, 16);
          float pn = pv / ss;
          cs += pn;
          int nloc = nloc0 + quad * 4 + r;
          sh.u.sa.attnT[l15][nloc] = (_Float16)pn;
          if (it == 2 && l15 < 8)
            P.out_attn[((size_t)(b * 12 + t) * 1024 + n0 + nloc) * 8 + l15] = pn;
        }
        cs += __shfl_xor(cs, 16); cs += __shfl_xor(cs, 32);
        if (lane < 8) atomicAdd(&sh.colsum[lane], cs);
      }
      __syncthreads();
      // ---- 4: partial updates = P^T @ v over local n (waves 0-7) -> global
      if (w < 8) {
        floatx4 acc = (floatx4){0.f, 0.f, 0.f, 0.f};
        const _Float16* ar = &sh.u.sa.attnT[l15][quad * 8];
        const _Float16* br = &sh.v_lds[w * 16 + l15][quad * 8];
        #pragma unroll
        for (int ks = 0; ks < 4; ks++)
          acc = MFMA_F16(*(const half8*)(ar + ks * 32), *(const half8*)(br + ks * 32), acc);
        int scol = w * 16 + l15;
        #pragma unroll
        for (int r = 0; r < 4; r++) {
          int slot = quad * 4 + r;
          if (slot < 8)
            __hip_atomic_store(&updg[slot * 128 + scol], acc[r],
                               __ATOMIC_RELAXED, __HIP_MEMORY_SCOPE_AGENT);
        }
      }
      if (tid < 8)
        __hip_atomic_store(&colg[tid], sh.colsum[tid],
                           __ATOMIC_RELAXED, __HIP_MEMORY_SCOPE_AGENT);
      // ---- 8-block barrier
      bar_phase++;
      group_barrier(ctrb, 8 * bar_phase);
      // ---- reduce partials; fold eps renorm -> a16
      {
        int slot = tid >> 7, scol = tid & 127;
        const float* up = P.upd_p + (size_t)(par * 16 + b) * 8 * 1024 + slot * 128 + scol;
        float sum = 0.f;
        #pragma unroll
        for (int gg = 0; gg < 8; gg++)
          sum += __hip_atomic_load((float*)(up + gg * 1024),
                                   __ATOMIC_RELAXED, __HIP_MEMORY_SCOPE_AGENT);
        float csum = 0.f;
        if (tid < 8) {
          const float* cp = P.col_p + (size_t)(par * 16 + b) * 8 * 8 + tid;
          #pragma unroll
          for (int gg = 0; gg < 8; gg++)
            csum += __hip_atomic_load((float*)(cp + gg * 8),
                                      __ATOMIC_RELAXED, __HIP_MEMORY_SCOPE_AGENT);
        }
        float vtot = 0.f;
        if (it == 0 && tid < 128) {
          const float* vp = P.vs_p + b * 8 * 128 + tid;
          #pragma unroll
          for (int gg = 0; gg < 8; gg++)
            vtot += __hip_atomic_load((float*)(vp + gg * 128),
                                      __ATOMIC_RELAXED, __HIP_MEMORY_SCOPE_AGENT);
        }
        __syncthreads();
        if (tid < 8) sh.colsum[tid] = csum;
        if (it == 0 && tid < 128) sh.vsum[tid] = vtot;
        __syncthreads();
        float upd = (sum + 1e-8f * sh.vsum[scol]) / (sh.colsum[slot] + 1024.f * 1e-8f);
        sh.a16[slot][scol] = (_Float16)upd;
        sh.a16[slot + 8][scol] = (_Float16)0.f;
      }
      __syncthreads();
      // ---- 5: GRU gemms
      for (int j = w; j < 48; j += 16) {
        int isGi = (j < 24) ? 1 : 0;
        int ct = isGi ? j : j - 24;
        const _Float16* Ap = isGi ? &sh.a16[0][0] : &sh.h16[0][0];
        const _Float16* Bg = (isGi ? P.Wih : P.Whh) + (size_t)(ct * 16 + l15) * 128 + quad * 8;
        const _Float16* ar = Ap + l15 * 136 + quad * 8;
        floatx4 acc = (floatx4){0.f, 0.f, 0.f, 0.f};
        #pragma unroll
        for (int ks = 0; ks < 4; ks++)
          acc = MFMA_F16(*(const half8*)(ar + ks * 32), *(const half8*)(Bg + ks * 32), acc);
        int col = ct * 16 + l15;
        float bias = isGi ? sh.bih[col] : sh.bhh[col];
        float* dst = isGi ? &sh.u.gru.gi[0][0] : &sh.u.gru.gh[0][0];
        #pragma unroll
        for (int r = 0; r < 4; r++) {
          int slot = quad * 4 + r;
          if (slot < 8) dst[slot * 384 + col] = acc[r] + bias;
        }
      }
      __syncthreads();
      // ---- 6: gates
      {
        int kk = tid >> 7, s = tid & 127;
        float gr = sh.u.gru.gi[kk][s]       + sh.u.gru.gh[kk][s];
        float gz = sh.u.gru.gi[kk][128 + s] + sh.u.gru.gh[kk][128 + s];
        float rg = 1.f / (1.f + expf(-gr));
        float zg = 1.f / (1.f + expf(-gz));
        float ng = tanhf(sh.u.gru.gi[kk][256 + s] + rg * sh.u.gru.gh[kk][256 + s]);
        float h = sh.slots[kk][s];
        sh.slots[kk][s] = (1.f - zg) * ng + zg * h;
      }
      __syncthreads();
      // ---- 7: residual MLP (iters 0,1)
      if (it < 2) {
        ln_to_a16(&sh, sh.slots, sh.lnmw, sh.lnmb, w, lane);
        __syncthreads();
        {
          floatx4 acc = (floatx4){0.f, 0.f, 0.f, 0.f};
          const _Float16* ar = &sh.a16[l15][quad * 8];
          const _Float16* br = P.W1T + (size_t)(w * 16 + l15) * 128 + quad * 8;
          #pragma unroll
          for (int ks = 0; ks < 4; ks++)
            acc = MFMA_F16(*(const half8*)(ar + ks * 32), *(const half8*)(br + ks * 32), acc);
          int col = w * 16 + l15;
          #pragma unroll
          for (int r = 0; r < 4; r++) {
            int slot = quad * 4 + r;
            if (slot < 8) sh.u.mlp.m16[slot][col] = (_Float16)fmaxf(acc[r] + sh.mb1[col], 0.f);
            else          sh.u.mlp.m16[slot][col] = (_Float16)0.f;
          }
        }
        __syncthreads();
        if (w < 8) {
          floatx4 acc = (floatx4){0.f, 0.f, 0.f, 0.f};
          const _Float16* ar = &sh.u.mlp.m16[l15][quad * 8];
          const _Float16* br = P.W2T + (size_t)(w * 16 + l15) * 256 + quad * 8;
          #pragma unroll
          for (int ks = 0; ks < 8; ks++)
            acc = MFMA_F16(*(const half8*)(ar + ks * 32), *(const half8*)(br + ks * 32), acc);
          int col = w * 16 + l15;
          #pragma unroll
          for (int r = 0; r < 4; r++) {
            int slot = quad * 4 + r;
            if (slot < 8) sh.slots[slot][col] += acc[r] + sh.mb2[col];
          }
        }
        __syncthreads();
      }
    } // it

    // collect slots (pre-predictor); only group 0 writes
    if (g == 0) {
      int kk = tid >> 7, s = tid & 127;
      P.out_slots[((size_t)(b * 12 + t) * 8 + kk) * 128 + s] = sh.slots[kk][s];
    }
    // ---- predictor (redundant, identical in all 8 blocks)
    ln_to_a16(&sh, sh.slots, sh.pl1w, sh.pl1b, w, lane);
    __syncthreads();
    for (int j = w; j < 24; j += 16) {
      int gg = j >> 3, ct = j & 7;
      const _Float16* Bg = (gg == 0 ? P.pQT : (gg == 1 ? P.pKT : P.pVT)) + (size_t)(ct * 16 + l15) * 128 + quad * 8;
      const _Float16* ar = &sh.a16[l15][quad * 8];
      floatx4 acc = (floatx4){0.f, 0.f, 0.f, 0.f};
      #pragma unroll
      for (int ks = 0; ks < 4; ks++)
        acc = MFMA_F16(*(const half8*)(ar + ks * 32), *(const half8*)(Bg + ks * 32), acc);
      float scale = (gg == 0) ? 0.17677669529663687f : 1.f;
      float* dst = (gg == 0 ? &sh.u.mha.qh[0][0] : (gg == 1 ? &sh.u.mha.kh[0][0] : &sh.u.mha.vh[0][0]));
      int col = ct * 16 + l15;
      #pragma unroll
      for (int r = 0; r < 4; r++) {
        int slot = quad * 4 + r;
        if (slot < 8) dst[slot * 128 + col] = acc[r] * scale;
      }
    }
    __syncthreads();
    if (tid < 256) {
      int h = tid >> 6, a = (tid >> 3) & 7, b2 = tid & 7;
      const float* qr = &sh.u.mha.qh[a][h * 32];
      const float* kr = &sh.u.mha.kh[b2][h * 32];
      float s = 0.f;
      #pragma unroll
      for (int d = 0; d < 32; d++) s += qr[d] * kr[d];
      sh.u.mha.sc[h][a][b2] = s;
    }
    __syncthreads();
    if (tid < 32) {
      int h = tid >> 3, a = tid & 7;
      float* p = sh.u.mha.sc[h][a];
      float mx = p[0];
      #pragma unroll
      for (int j = 1; j < 8; j++) mx = fmaxf(mx, p[j]);
      float e[8]; float ssum = 0.f;
      #pragma unroll
      for (int j = 0; j < 8; j++) { e[j] = expf(p[j] - mx); ssum += e[j]; }
      float inv = 1.f / ssum;
      #pragma unroll
      for (int j = 0; j < 8; j++) p[j] = e[j] * inv;
    }
    __syncthreads();
    {
      int a = tid >> 7, col = tid & 127, h = col >> 5;
      float acc = 0.f;
      #pragma unroll
      for (int b2 = 0; b2 < 8; b2++) acc += sh.u.mha.sc[h][a][b2] * sh.u.mha.vh[b2][col];
      sh.a16[a][col] = (_Float16)acc;
    }
    __syncthreads();
    if (w < 8) {       // s += o @ Wo
      floatx4 acc = (floatx4){0.f, 0.f, 0.f, 0.f};
      const _Float16* ar = &sh.a16[l15][quad * 8];
      const _Float16* br = P.pOT + (size_t)(w * 16 + l15) * 128 + quad * 8;
      #pragma unroll
      for (int ks = 0; ks < 4; ks++)
        acc = MFMA_F16(*(const half8*)(ar + ks * 32), *(const half8*)(br + ks * 32), acc);
      int col = w * 16 + l15;
      #pragma unroll
      for (int r = 0; r < 4; r++) {
        int slot = quad * 4 + r;
        if (slot < 8) sh.slots[slot][col] += acc[r];
      }
    }
    __syncthreads();
    ln_to_a16(&sh, sh.slots, sh.pl2w, sh.pl2b, w, lane);
    __syncthreads();
    for (int ct = w; ct < 32; ct += 16) {   // FFN1 + relu
      floatx4 acc = (floatx4){0.f, 0.f, 0.f, 0.f};
      const _Float16* ar = &sh.a16[l15][quad * 8];
      const _Float16* br = P.pF1T + (size_t)(ct * 16 + l15) * 128 + quad * 8;
      #pragma unroll
      for (int ks = 0; ks < 4; ks++)
        acc = MFMA_F16(*(const half8*)(ar + ks * 32), *(const half8*)(br + ks * 32), acc);
      int col = ct * 16 + l15;
      #pragma unroll
      for (int r = 0; r < 4; r++) {
        int slot = quad * 4 + r;
        if (slot < 8) sh.u.ffn.f16[slot][col] = (_Float16)fmaxf(acc[r] + sh.fb1[col], 0.f);
        else          sh.u.ffn.f16[slot][col] = (_Float16)0.f;
      }
    }
    __syncthreads();
    if (w < 8) {       // FFN2 + residual
      floatx4 acc = (floatx4){0.f, 0.f, 0.f, 0.f};
      const _Float16* ar = &sh.u.ffn.f16[l15][quad * 8];
      const _Float16* br = P.pF2T + (size_t)(w * 16 + l15) * 512 + quad * 8;
      #pragma unroll 4
      for (int ks = 0; ks < 16; ks++)
        acc = MFMA_F16(*(const half8*)(ar + ks * 32), *(const half8*)(br + ks * 32), acc);
      int col = w * 16 + l15;
      #pragma unroll
      for (int r = 0; r < 4; r++) {
        int slot = quad * 4 + r;
        if (slot < 8) sh.slots[slot][col] += acc[r] + sh.fb2[col];
      }
    }
    __syncthreads();
    if (w < 8) {       // final LN -> carry
      float x0 = sh.slots[w][lane], x1 = sh.slots[w][lane + 64];
      float s = x0 + x1, sq = x0 * x0 + x1 * x1;
      #pragma unroll
      for (int m = 1; m < 64; m <<= 1) { s += __shfl_xor(s, m); sq += __shfl_xor(sq, m); }
      float mn = s * 0.0078125f;
      float vr = sq * 0.0078125f - mn * mn;
      float rs = rsqrtf(vr + 1e-5f);
      sh.slots[w][lane]      = (x0 - mn) * rs * sh.plfw[lane]      + sh.plfb[lane];
      sh.slots[w][lane + 64] = (x1 - mn) * rs * sh.plfw[lane + 64] + sh.plfb[lane + 64];
    }
    __syncthreads();
  } // t
}

// ---------------------------------------------------------------------------
extern "C" void kernel_launch(void* const* d_in, const int* in_sizes, int n_in,
                              void* d_out, int out_size, void* d_ws, size_t ws_size,
                              hipStream_t stream) {
  const float* inp   = (const float*)d_in[0];
  const float* noise = (const float*)d_in[1];
  const float* mu    = (const float*)d_in[2];
  const float* lsig  = (const float*)d_in[3];
  const float* lniw  = (const float*)d_in[4];
  const float* lnib  = (const float*)d_in[5];
  const float* lnsw  = (const float*)d_in[6];
  const float* lnsb  = (const float*)d_in[7];
  const float* lnmw  = (const float*)d_in[8];
  const float* lnmb  = (const float*)d_in[9];
  const float* Wq    = (const float*)d_in[10];
  const float* Wk    = (const float*)d_in[11];
  const float* Wv    = (const float*)d_in[12];
  const float* gWih  = (const float*)d_in[13];
  const float* gWhh  = (const float*)d_in[14];
  const float* gbih  = (const float*)d_in[15];
  const float* gbhh  = (const float*)d_in[16];
  const float* mW1   = (const float*)d_in[17];
  const float* mb1   = (const float*)d_in[18];
  const float* mW2   = (const float*)d_in[19];
  const float* mb2   = (const float*)d_in[20];
  const float* pl1w  = (const float*)d_in[21];
  const float* pl1b  = (const float*)d_in[22];
  const float* pWq   = (const float*)d_in[23];
  const float* pWk   = (const float*)d_in[24];
  const float* pWv   = (const float*)d_in[25];
  const float* pWo   = (const float*)d_in[26];
  const float* pl2w  = (const float*)d_in[27];
  const float* pl2b  = (const float*)d_in[28];
  const float* pf1   = (const float*)d_in[29];
  const float* pfb1  = (const float*)d_in[30];
  const float* pf2   = (const float*)d_in[31];
  const float* pfb2  = (const float*)d_in[32];
  const float* plfw  = (const float*)d_in[33];
  const float* plfb  = (const float*)d_in[34];

  // workspace layout (f16 elements); ~101.5 MB + ~0.6 MB partials
  _Float16* p   = (_Float16*)d_ws;
  _Float16* kbuf = p;  p += 25165824;
  _Float16* vT   = p;  p += 25165824;
  _Float16* WT   = p;  p += 65536;
  _Float16* WqT  = p;  p += 16384;
  _Float16* Wih  = p;  p += 49152;
  _Float16* Whh  = p;  p += 49152;
  _Float16* W1T  = p;  p += 32768;
  _Float16* W2T  = p;  p += 32768;
  _Float16* pQT  = p;  p += 16384;
  _Float16* pKT  = p;  p += 16384;
  _Float16* pVT  = p;  p += 16384;
  _Float16* pOT  = p;  p += 16384;
  _Float16* pF1T = p;  p += 65536;
  _Float16* pF2T = p;  p += 65536;
  float* fb   = (float*)p;
  float* upd_p = fb;  fb += 2 * 16 * 8 * 1024;   // 131072
  float* col_p = fb;  fb += 2 * 16 * 8 * 8;      // 2048
  float* vs_p  = fb;  fb += 16 * 8 * 128;        // 16384
  int*   ctr   = (int*)fb;                       // 16

  const float kscale = 0.08838834764831845f;  // S^-0.5, S=128
  init_ctr_kernel<<<1, 64, 0, stream>>>(ctr);
  prep_w_kernel<<<128, 256, 0, stream>>>(Wk,   WT,         256, 128, kscale, 1);
  prep_w_kernel<<<128, 256, 0, stream>>>(Wv,   WT + 32768, 256, 128, 1.f,    1);
  prep_w_kernel<<<64,  256, 0, stream>>>(Wq,   WqT,        128, 128, 1.f,    1);
  prep_w_kernel<<<192, 256, 0, stream>>>(gWih, Wih,        49152, 1, 1.f,    0);
  prep_w_kernel<<<192, 256, 0, stream>>>(gWhh, Whh,        49152, 1, 1.f,    0);
  prep_w_kernel<<<128, 256, 0, stream>>>(mW1,  W1T,        128, 256, 1.f,    1);
  prep_w_kernel<<<128, 256, 0, stream>>>(mW2,  W2T,        256, 128, 1.f,    1);
  prep_w_kernel<<<64,  256, 0, stream>>>(pWq,  pQT,        128, 128, 1.f,    1);
  prep_w_kernel<<<64,  256, 0, stream>>>(pWk,  pKT,        128, 128, 1.f,    1);
  prep_w_kernel<<<64,  256, 0, stream>>>(pWv,  pVT,        128, 128, 1.f,    1);
  prep_w_kernel<<<64,  256, 0, stream>>>(pWo,  pOT,        128, 128, 1.f,    1);
  prep_w_kernel<<<256, 256, 0, stream>>>(pf1,  pF1T,       128, 512, 1.f,    1);
  prep_w_kernel<<<256, 256, 0, stream>>>(pf2,  pF2T,       512, 128, 1.f,    1);

  dim3 g1(1536, 2, 1);
  gemm_kv_kernel<<<g1, 256, 0, stream>>>(inp, lniw, lnib, WT, kbuf, vT);

  P2Args a;
  a.kbuf = kbuf; a.vT = vT;
  a.WqT = WqT; a.Wih = Wih; a.Whh = Whh; a.W1T = W1T; a.W2T = W2T;
  a.pQT = pQT; a.pKT = pKT; a.pVT = pVT; a.pOT = pOT; a.pF1T = pF1T; a.pF2T = pF2T;
  a.noise = noise; a.mu = mu; a.lsig = lsig;
  a.lnsw = lnsw; a.lnsb = lnsb; a.lnmw = lnmw; a.lnmb = lnmb;
  a.bih = gbih; a.bhh = gbhh; a.mb1 = mb1; a.mb2 = mb2;
  a.pl1w = pl1w; a.pl1b = pl1b; a.pl2w = pl2w; a.pl2b = pl2b;
  a.fb1 = pfb1; a.fb2 = pfb2; a.plfw = plfw; a.plfb = plfb;
  a.out_slots = (float*)d_out;
  a.out_attn  = (float*)d_out + 196608;
  a.upd_p = upd_p; a.col_p = col_p; a.vs_p = vs_p; a.ctr = ctr;

  slot_attn_kernel<<<128, 1024, 0, stream>>>(a);
}